// Round 22
// baseline (38.329 us; speedup 1.0000x reference)
//
#include <hip/hip_runtime.h>
#include <math.h>

#define CDIM   862
#define NRANK  8
#define KW     7
#define WAVES  4
#define THREADS (WAVES * 64)
#define RPB    (WAVES * 2)   // 8 rows per block (2 rows per wave)
#define LN_EPS 1e-5f
#define NTILE  7             // 7 quad-tiles x 128 elements cover [-1,894] >= [0,861]
#define XH_LEN 912           // shorts: [0..3]=x[-4..-1]=0, [4+i]=bf16(x[i]), zeros to 911
#define XY_LEN 866           // f32: x (overwritten by pre-norm y) + pad

typedef __attribute__((ext_vector_type(8)))  short bf16x8;
typedef __attribute__((ext_vector_type(16))) float f32x16;

static __device__ __forceinline__ unsigned rne_bf16(float f) {
    const unsigned u = __float_as_uint(f);
    return (u + 0x7FFFu + ((u >> 16) & 1u)) >> 16;   // round-to-nearest-even
}

// v_exp_f32 IS 2^x on gfx950 (r20-validated). Fallback exact.
#if __has_builtin(__builtin_amdgcn_exp2f)
#define EXP2F(x) __builtin_amdgcn_exp2f(x)
#else
#define EXP2F(x) __expf((x) * 0.69314718055994530942f)
#endif

// TWO ROWS PER WAVE, quad-tile MFMA (r21-validated mapping). r21 showed the
// kernel is latency-bound on the per-tile serial chain (VALUBusy 49%, census
// ~11us issue vs 36us wall): one dependency chain per wave, ~2.75 waves/SIMD.
// This round doubles per-wave ILP by interleaving two independent rows (A,B)
// in each wave -- same verified per-row math/mapping, two register sets, the
// scheduler overlaps the chains. Occupancy levers (r8,r12) and scheduler
// steering (r9,r11) both failed; ILP-by-structure (r10) is the proven lever.
//   A(32x16): rows 0-7 taps k=0..6 -> conv(E0), rows 8-15 k=8..14 -> conv(E2),
//   rows 16-23 k=1..7 -> conv(E0+1), rows 24-31 k=9..15 -> conv(E2+1);
//   B col l31: k=0..7 = win(E0) [hh=0 lanes], k=8..15 = win(E2) [hh=1].
//   E0 = 128s+2*l31-1 odd -> window = 4 ALIGNED dwords, no alignbit.
//   D: d[0..3]=E0, d[4..7]=E2, d[8..11]=E1, d[12..15]=E3 (ranks 4hh..4hh+3).
__global__ __launch_bounds__(THREADS) void cvmc_kernel(
    const float* __restrict__ x,
    const float* __restrict__ Wup,
    const float* __restrict__ bup,
    const float* __restrict__ Wdown,
    const float* __restrict__ bdown,
    const float* __restrict__ gamma,
    const float* __restrict__ beta,
    float* __restrict__ out)
{
    const int lane = threadIdx.x & 63;
    const int wv   = threadIdx.x >> 6;
    const int rowA = (blockIdx.x * WAVES + wv) * 2;
    const int rowB = rowA + 1;

    __shared__ short sxh[RPB][XH_LEN];
    __shared__ float sxy[RPB][XY_LEN];
    const int sA = 2 * wv, sB = 2 * wv + 1;

    const int hh    = lane >> 5;
    const int l31   = lane & 31;
    const int rbase = 4 * hh;          // this half-wave's rank group
    float bu4[4], wd4[4];
#pragma unroll
    for (int q = 0; q < 4; ++q) {
        bu4[q] = bup[rbase + q];
        wd4[q] = Wdown[rbase + q];
    }

    // ---- A fragment: 4 row-groups, tap shift by group (r21-verified) ----
    bf16x8 afrag;
    {
        const int r    = l31 & 7;
        const int grp  = l31 >> 3;             // 0..3
        const bool use = ((grp & 1) == hh);    // grp0,2 in hh=0 slots; 1,3 in hh=1
        const int  sft = grp >> 1;             // shift-by-one for E+1 rows
#pragma unroll
        for (int j = 0; j < 8; ++j) {
            const int tap = j - sft;
            float wvv = (use && tap >= 0 && tap < KW) ? Wup[r * KW + tap] : 0.0f;
            afrag[j] = (short)(rne_bf16(wvv) & 0xFFFFu);
        }
    }

    // ---- C operand: bias (rank of D row = (reg&3)+4hh for every group) ----
    f32x16 cin;
#pragma unroll
    for (int i = 0; i < 16; ++i) cin[i] = bu4[i & 3];

    // ---- stage BOTH rows: sxy = f32 x, sxh = bf16(RNE), pads zeroed ----
    {
        const float2* __restrict__ xrA =
            reinterpret_cast<const float2*>(x + (size_t)rowA * CDIM);
        const float2* __restrict__ xrB =
            reinterpret_cast<const float2*>(x + (size_t)rowB * CDIM);
        unsigned* xhWA = reinterpret_cast<unsigned*>(&sxh[sA][0]);
        unsigned* xhWB = reinterpret_cast<unsigned*>(&sxh[sB][0]);
#pragma unroll
        for (int qq = 0; qq < 7; ++qq) {
            const int i = lane + 64 * qq;               // float2 pair index
            if (i < CDIM / 2) {
                float2 va = xrA[i];
                float2 vb = xrB[i];
                *reinterpret_cast<float2*>(&sxy[sA][2 * i]) = va;
                *reinterpret_cast<float2*>(&sxy[sB][2 * i]) = vb;
                xhWA[2 + i] = rne_bf16(va.x) | (rne_bf16(va.y) << 16);
                xhWB[2 + i] = rne_bf16(vb.x) | (rne_bf16(vb.y) << 16);
            }
        }
        if (lane < 2)        { xhWA[lane] = 0u; xhWB[lane] = 0u; }
        else if (lane < 25)  { xhWA[431 + lane] = 0u; xhWB[431 + lane] = 0u; }
        else if (lane < 29)  { sxy[sA][862 + (lane - 25)] = 0.0f;
                               sxy[sB][862 + (lane - 25)] = 0.0f; }
    }
    // wave-private LDS slices; same-wave DS ops complete in issue order -> no barrier

    // gelu(t) ~ t*sigmoid(1.5957691 t + 0.0713548 t^3); u = 1 + 2^z (log2e folded)
    const float C1 = -0.0713548162f * 1.44269504088896340736f;
    const float C0 = -1.5957691216f * 1.44269504088896340736f;

    const unsigned* xhDA = reinterpret_cast<const unsigned*>(&sxh[sA][0]);
    const unsigned* xhDB = reinterpret_cast<const unsigned*>(&sxh[sB][0]);

    auto dp4 = [&](float t0, float t1, float t2, float t3) -> float {
        const float z0 = t0 * fmaf(t0 * t0, C1, C0);
        const float z1 = t1 * fmaf(t1 * t1, C1, C0);
        const float z2 = t2 * fmaf(t2 * t2, C1, C0);
        const float z3 = t3 * fmaf(t3 * t3, C1, C0);
        const float u0 = 1.0f + EXP2F(z0);
        const float u1 = 1.0f + EXP2F(z1);
        const float u2 = 1.0f + EXP2F(z2);
        const float u3 = 1.0f + EXP2F(z3);
        const float r01 = __builtin_amdgcn_rcpf(u0 * u1);
        const float r23 = __builtin_amdgcn_rcpf(u2 * u3);
        float n0 = (wd4[0] * t0) * u1; n0 = fmaf(wd4[1] * t1, u0, n0);
        float n1 = (wd4[2] * t2) * u3; n1 = fmaf(wd4[3] * t3, u2, n1);
        float p  = n0 * r01;
        return fmaf(n1, r23, p);
    };

    float sumA = 0.0f, sumsqA = 0.0f;
    float sumB = 0.0f, sumsqB = 0.0f;

    for (int s = 0; s < NTILE; ++s) {
        const int w = 64 * s + lane;
        union { unsigned u[4]; bf16x8 v; } bfA, bfB;
        bfA.u[0] = xhDA[w];     bfA.u[1] = xhDA[w + 1];
        bfA.u[2] = xhDA[w + 2]; bfA.u[3] = xhDA[w + 3];
        bfB.u[0] = xhDB[w];     bfB.u[1] = xhDB[w + 1];
        bfB.u[2] = xhDB[w + 2]; bfB.u[3] = xhDB[w + 3];

        f32x16 dA = __builtin_amdgcn_mfma_f32_32x32x16_bf16(afrag, bfA.v, cin, 0, 0, 0);
        f32x16 dB = __builtin_amdgcn_mfma_f32_32x32x16_bf16(afrag, bfB.v, cin, 0, 0, 0);

        // row A
        const float pA0 = dp4(dA[0],  dA[1],  dA[2],  dA[3]);
        const float pA2 = dp4(dA[4],  dA[5],  dA[6],  dA[7]);
        const float pA1 = dp4(dA[8],  dA[9],  dA[10], dA[11]);
        const float pA3 = dp4(dA[12], dA[13], dA[14], dA[15]);
        // row B
        const float pB0 = dp4(dB[0],  dB[1],  dB[2],  dB[3]);
        const float pB2 = dp4(dB[4],  dB[5],  dB[6],  dB[7]);
        const float pB1 = dp4(dB[8],  dB[9],  dB[10], dB[11]);
        const float pB3 = dp4(dB[12], dB[13], dB[14], dB[15]);

        const float hA0 = pA0 + __shfl_xor(pA0, 32, 64);
        const float hA2 = pA2 + __shfl_xor(pA2, 32, 64);
        const float hA1 = pA1 + __shfl_xor(pA1, 32, 64);
        const float hA3 = pA3 + __shfl_xor(pA3, 32, 64);
        const float hB0 = pB0 + __shfl_xor(pB0, 32, 64);
        const float hB2 = pB2 + __shfl_xor(pB2, 32, 64);
        const float hB1 = pB1 + __shfl_xor(pB1, 32, 64);
        const float hB3 = pB3 + __shfl_xor(pB3, 32, 64);

        // ownership: hh=0 finalizes (E0,E1); hh=1 finalizes (E2,E3)
        const int   eS  = 128 * s + 2 * l31 - 1 + 64 * hh;
        const float a0 = hh ? hA2 : hA0;
        const float a1 = hh ? hA3 : hA1;
        const float b0 = hh ? hB2 : hB0;
        const float b1 = hh ? hB3 : hB1;

        if ((unsigned)eS < CDIM) {
            const float ya = sxy[sA][eS] + a0;
            sxy[sA][eS] = ya;
            sumA += ya; sumsqA = fmaf(ya, ya, sumsqA);
            const float yb = sxy[sB][eS] + b0;
            sxy[sB][eS] = yb;
            sumB += yb; sumsqB = fmaf(yb, yb, sumsqB);
        }
        if ((unsigned)(eS + 1) < CDIM) {
            const float ya = sxy[sA][eS + 1] + a1;
            sxy[sA][eS + 1] = ya;
            sumA += ya; sumsqA = fmaf(ya, ya, sumsqA);
            const float yb = sxy[sB][eS + 1] + b1;
            sxy[sB][eS + 1] = yb;
            sumB += yb; sumsqB = fmaf(yb, yb, sumsqB);
        }
    }

    // in-wave butterflies: every lane ends with both rows' totals
#pragma unroll
    for (int off = 1; off < 64; off <<= 1) {
        sumA   += __shfl_xor(sumA, off, 64);
        sumsqA += __shfl_xor(sumsqA, off, 64);
        sumB   += __shfl_xor(sumB, off, 64);
        sumsqB += __shfl_xor(sumsqB, off, 64);
    }

    const float inv   = 1.0f / (float)CDIM;
    const float muA   = sumA * inv;
    const float varA  = fmaf(sumsqA, inv, -muA * muA);
    const float rstdA = rsqrtf(varA + LN_EPS);
    const float muB   = sumB * inv;
    const float varB  = fmaf(sumsqB, inv, -muB * muB);
    const float rstdB = rsqrtf(varB + LN_EPS);

    // coalesced epilogue: contiguous float2 reads from LDS, float2 stores
    float2* __restrict__ yrA = reinterpret_cast<float2*>(out + (size_t)rowA * CDIM);
    float2* __restrict__ yrB = reinterpret_cast<float2*>(out + (size_t)rowB * CDIM);
    const float2* __restrict__ g2 = reinterpret_cast<const float2*>(gamma);
    const float2* __restrict__ b2 = reinterpret_cast<const float2*>(beta);
#pragma unroll
    for (int qq = 0; qq < 7; ++qq) {
        const int i = lane + 64 * qq;
        if (i < CDIM / 2) {
            const float2 gv = g2[i];
            const float2 bv = b2[i];
            const float2 ya = *reinterpret_cast<const float2*>(&sxy[sA][2 * i]);
            const float2 yb = *reinterpret_cast<const float2*>(&sxy[sB][2 * i]);
            float2 oa, ob;
            oa.x = fmaf((ya.x - muA) * rstdA, gv.x, bv.x);
            oa.y = fmaf((ya.y - muA) * rstdA, gv.y, bv.y);
            ob.x = fmaf((yb.x - muB) * rstdB, gv.x, bv.x);
            ob.y = fmaf((yb.y - muB) * rstdB, gv.y, bv.y);
            yrA[i] = oa;
            yrB[i] = ob;
        }
    }
}

extern "C" void kernel_launch(void* const* d_in, const int* in_sizes, int n_in,
                              void* d_out, int out_size, void* d_ws, size_t ws_size,
                              hipStream_t stream) {
    const float* x     = (const float*)d_in[0];
    const float* Wup   = (const float*)d_in[1];
    const float* bup   = (const float*)d_in[2];
    const float* Wdown = (const float*)d_in[3];
    const float* bdown = (const float*)d_in[4];   // cancels in LayerNorm; unused
    const float* gamma = (const float*)d_in[5];
    const float* beta  = (const float*)d_in[6];
    float* out = (float*)d_out;
    (void)bdown;

    const int nrows = out_size / CDIM;                 // 11520 (divisible by 8)
    const int nblk  = nrows / RPB;                     // 1440
    cvmc_kernel<<<nblk, THREADS, 0, stream>>>(x, Wup, bup, Wdown, bdown,
                                              gamma, beta, out);
}

// Round 23
// 35.993 us; speedup vs baseline: 1.0649x; 1.0649x over previous
//
#include <hip/hip_runtime.h>
#include <math.h>

#define CDIM   862
#define NRANK  8
#define KW     7
#define ROWS_PER_BLOCK 4
#define THREADS (ROWS_PER_BLOCK * 64)
#define LN_EPS 1e-5f
#define NTILE  7             // 7 quad-tiles x 128 elements cover [-1,894] >= [0,861]
#define XH_LEN 912           // shorts: [0..3]=x[-4..-1]=0, [4+i]=bf16(x[i]), zeros to 911
#define XY_LEN 866           // f32: x (overwritten by pre-norm y) + pad

typedef __attribute__((ext_vector_type(8)))  short bf16x8;
typedef __attribute__((ext_vector_type(16))) float f32x16;

static __device__ __forceinline__ unsigned rne_bf16(float f) {
    const unsigned u = __float_as_uint(f);
    return (u + 0x7FFFu + ((u >> 16) & 1u)) >> 16;   // round-to-nearest-even
}

// v_exp_f32 IS 2^x on gfx950 (r20-validated). Fallback exact.
#if __has_builtin(__builtin_amdgcn_exp2f)
#define EXP2F(x) __builtin_amdgcn_exp2f(x)
#else
#define EXP2F(x) __expf((x) * 0.69314718055994530942f)
#endif

// One wave = one row. SHUFFLE-FREE quad-tile MFMA. D layout (m74/m101):
// row=(reg&3)+8*(reg>>2)+4*hh => hh=0 lanes read rows {0-3,8-11,16-19,24-27},
// hh=1 read {4-7,12-15,20-23,28-31}. A-row assignment puts ALL 8 ranks of one
// element into ONE lane's registers:
//   rows  0- 3: ranks 0-3, taps k=0..6   | rows  8-11: ranks 4-7, k=0..6
//   rows  4- 7: ranks 0-3, taps k=1..7   | rows 12-15: ranks 4-7, k=1..7
//   rows 16-19: ranks 0-3, taps k=8..14  | rows 24-27: ranks 4-7, k=8..14
//   rows 20-23: ranks 0-3, taps k=9..15  | rows 28-31: ranks 4-7, k=9..15
// B col c: k=0..7 slots = win(E0(c)), k=8..15 = win(E2(c)), E0 = 128s+2c-1.
// => hh=0 lane: d[0..7] = ranks 0-7 of E0, d[8..15] = of E2 = E0+64.
//    hh=1 lane: d[0..7] = ranks 0-7 of E1 = E0+1, d[8..15] = of E3.
// h per element is fully lane-local (dp8) -- ZERO shuffles in the loop
// (r21 spent 4 ds_bpermute/tile in the serial chain). cin[q] = bup[q&7]
// uniform. Ownership: lane finalizes eS0 = 128s+2*l31-1+hh and eS0+64;
// (unsigned)e < 862 masks edges. GELU math identical to r20/r21 (PASS'd).
__global__ __launch_bounds__(THREADS) void cvmc_kernel(
    const float* __restrict__ x,
    const float* __restrict__ Wup,
    const float* __restrict__ bup,
    const float* __restrict__ Wdown,
    const float* __restrict__ bdown,
    const float* __restrict__ gamma,
    const float* __restrict__ beta,
    float* __restrict__ out)
{
    const int lane = threadIdx.x & 63;
    const int wv   = threadIdx.x >> 6;
    const int row  = blockIdx.x * ROWS_PER_BLOCK + wv;

    __shared__ short sxh[ROWS_PER_BLOCK][XH_LEN];
    __shared__ float sxy[ROWS_PER_BLOCK][XY_LEN];

    const int hh  = lane >> 5;
    const int l31 = lane & 31;

    // all 8 rank weights per lane (wave-uniform -> SGPR)
    float bu8[NRANK], wd8[NRANK];
#pragma unroll
    for (int q = 0; q < NRANK; ++q) {
        bu8[q] = bup[q];
        wd8[q] = Wdown[q];
    }

    // ---- A fragment: row = l31, k-slot k = 8*hh + j ----
    // row's content: rank = (l31&3) + 4*((l31>>3)&1); shift = (l31>>2)&1;
    // k-half owner: (l31>>4) must equal hh; tap = j - shift.
    bf16x8 afrag;
    {
        const int  rr   = (l31 & 3) + 4 * ((l31 >> 3) & 1);
        const int  sft  = (l31 >> 2) & 1;
        const bool use  = ((l31 >> 4) == hh);
#pragma unroll
        for (int j = 0; j < 8; ++j) {
            const int tap = j - sft;
            float wvv = (use && tap >= 0 && tap < KW) ? Wup[rr * KW + tap] : 0.0f;
            afrag[j] = (short)(rne_bf16(wvv) & 0xFFFFu);
        }
    }

    // ---- C operand: bias; rank of reg q is q&7 for every lane ----
    f32x16 cin;
#pragma unroll
    for (int i = 0; i < 16; ++i) cin[i] = bu8[i & 7];

    // ---- stage row: sxy = f32 x, sxh = bf16(RNE), pads zeroed ----
    {
        const float2* __restrict__ xr2 =
            reinterpret_cast<const float2*>(x + (size_t)row * CDIM);
        unsigned* xhW = reinterpret_cast<unsigned*>(&sxh[wv][0]);
#pragma unroll
        for (int qq = 0; qq < 7; ++qq) {
            const int i = lane + 64 * qq;               // float2 pair index
            if (i < CDIM / 2) {
                float2 v = xr2[i];
                *reinterpret_cast<float2*>(&sxy[wv][2 * i]) = v;
                xhW[2 + i] = rne_bf16(v.x) | (rne_bf16(v.y) << 16);
            }
        }
        if (lane < 2)        xhW[lane] = 0u;            // shorts 0..3 = x[-4..-1]
        else if (lane < 25)  xhW[431 + lane] = 0u;      // dwords 433..455 zero
        else if (lane < 29)  sxy[wv][862 + (lane - 25)] = 0.0f;
    }
    // wave-private LDS slice; same-wave DS ops complete in issue order -> no barrier

    // gelu(t) ~ t*sigmoid(1.5957691 t + 0.0713548 t^3); u = 1 + 2^z (log2e folded)
    const float C1 = -0.0713548162f * 1.44269504088896340736f;
    const float C0 = -1.5957691216f * 1.44269504088896340736f;

    const unsigned* xhD = reinterpret_cast<const unsigned*>(&sxh[wv][0]);

    // full 8-rank GELU + down-proj, lane-local (rank-paired rcp as r15-r21)
    auto dp8 = [&](const float* t) -> float {
        float u[NRANK];
#pragma unroll
        for (int r = 0; r < NRANK; ++r) {
            const float z = t[r] * fmaf(t[r] * t[r], C1, C0);
            u[r] = 1.0f + EXP2F(z);
        }
        float h = 0.0f;
#pragma unroll
        for (int rp = 0; rp < NRANK / 2; ++rp) {
            const float ua = u[2 * rp], ub = u[2 * rp + 1];
            const float rr = __builtin_amdgcn_rcpf(ua * ub);
            float n = (wd8[2 * rp] * t[2 * rp]) * ub;
            n = fmaf(wd8[2 * rp + 1] * t[2 * rp + 1], ua, n);
            h = fmaf(n, rr, h);
        }
        return h;
    };

    float sum = 0.0f, sumsq = 0.0f;

    for (int s = 0; s < NTILE; ++s) {
        // this lane's window: 4 aligned dwords (8 bf16) -- its k-half of column l31
        const int w = 64 * s + lane;
        union { unsigned u[4]; bf16x8 v; } bfr;
        bfr.u[0] = xhD[w];
        bfr.u[1] = xhD[w + 1];
        bfr.u[2] = xhD[w + 2];
        bfr.u[3] = xhD[w + 3];

        f32x16 d = __builtin_amdgcn_mfma_f32_32x32x16_bf16(afrag, bfr.v, cin, 0, 0, 0);

        float t0[NRANK], t1[NRANK];
#pragma unroll
        for (int r = 0; r < NRANK; ++r) { t0[r] = d[r]; t1[r] = d[8 + r]; }

        const float h0 = dp8(t0);      // all 8 ranks of eS0 -- no shuffle
        const float h1 = dp8(t1);      // all 8 ranks of eS0+64

        const int eS0 = 128 * s + 2 * l31 - 1 + hh;   // hh=0: E0 (odd), hh=1: E1 (even)
        const int eS1 = eS0 + 64;

        if ((unsigned)eS0 < CDIM) {
            const float y = sxy[wv][eS0] + h0;
            sxy[wv][eS0] = y;
            sum += y;
            sumsq = fmaf(y, y, sumsq);
        }
        if ((unsigned)eS1 < CDIM) {
            const float y = sxy[wv][eS1] + h1;
            sxy[wv][eS1] = y;
            sum += y;
            sumsq = fmaf(y, y, sumsq);
        }
    }

    // in-wave butterfly: every lane ends with the row totals
#pragma unroll
    for (int off = 1; off < 64; off <<= 1) {
        sum   += __shfl_xor(sum, off, 64);
        sumsq += __shfl_xor(sumsq, off, 64);
    }

    const float inv  = 1.0f / (float)CDIM;
    const float mu   = sum * inv;
    const float var  = fmaf(sumsq, inv, -mu * mu);
    const float rstd = rsqrtf(var + LN_EPS);

    // coalesced epilogue: contiguous float2 reads from LDS, float2 stores
    float2* __restrict__ yr2 = reinterpret_cast<float2*>(out + (size_t)row * CDIM);
    const float2* __restrict__ g2 = reinterpret_cast<const float2*>(gamma);
    const float2* __restrict__ b2 = reinterpret_cast<const float2*>(beta);
#pragma unroll
    for (int qq = 0; qq < 7; ++qq) {
        const int i = lane + 64 * qq;
        if (i < CDIM / 2) {
            const float2 yv = *reinterpret_cast<const float2*>(&sxy[wv][2 * i]);
            const float2 gv = g2[i];
            const float2 bv = b2[i];
            float2 o;
            o.x = fmaf((yv.x - mu) * rstd, gv.x, bv.x);
            o.y = fmaf((yv.y - mu) * rstd, gv.y, bv.y);
            yr2[i] = o;
        }
    }
}

extern "C" void kernel_launch(void* const* d_in, const int* in_sizes, int n_in,
                              void* d_out, int out_size, void* d_ws, size_t ws_size,
                              hipStream_t stream) {
    const float* x     = (const float*)d_in[0];
    const float* Wup   = (const float*)d_in[1];
    const float* bup   = (const float*)d_in[2];
    const float* Wdown = (const float*)d_in[3];
    const float* bdown = (const float*)d_in[4];   // cancels in LayerNorm; unused
    const float* gamma = (const float*)d_in[5];
    const float* beta  = (const float*)d_in[6];
    float* out = (float*)d_out;
    (void)bdown;

    const int nrows = out_size / CDIM;                 // 11520 (divisible by 4)
    const int nblk  = nrows / ROWS_PER_BLOCK;          // 2880
    cvmc_kernel<<<nblk, THREADS, 0, stream>>>(x, Wup, bup, Wdown, bdown,
                                              gamma, beta, out);
}